// Round 10
// baseline (427.542 us; speedup 1.0000x reference)
//
#include <hip/hip_runtime.h>

// ---------------------------------------------------------------------------
// GraphConv (DGL norm='both') + residual linear:
//   out = (D_dst^-1/2 * A^T * (D_src^-1/2 * x)) @ W + x @ Wr + (b + br)
// Round 10: 64-node range bucketing; aggregation directly into LDS
// accumulators (no CSR, no col array, no gather kernel); packed edge words;
// fused outdeg+prescale. Zero global atomics, zero memsets, 8 launches.
// ---------------------------------------------------------------------------

#define TILE 4096   // edges per bucket block
#define RB   64     // nodes per range

// Per-block LDS histograms of dst>>6 and src>>6.
// H layout: H[bin*nb + blk] (dst bins 0..1023), H[(1024+bin)*nb + blk] (src).
__global__ __launch_bounds__(256) void bucket_hist_kernel(
    const int* __restrict__ src, const int* __restrict__ dst,
    int* __restrict__ H, int e, int nb) {
    __shared__ int hd[1024], hs[1024];
    int t = threadIdx.x, blk = blockIdx.x;
    for (int i = t; i < 1024; i += 256) { hd[i] = 0; hs[i] = 0; }
    __syncthreads();
    int base = blk * TILE;
    #pragma unroll
    for (int s2 = 0; s2 < 16; ++s2) {
        int j = base + s2 * 256 + t;
        if (j < e) {
            atomicAdd(&hd[dst[j] >> 6], 1);
            atomicAdd(&hs[src[j] >> 6], 1);
        }
    }
    __syncthreads();
    for (int i = t; i < 1024; i += 256) {
        H[i * nb + blk]          = hd[i];
        H[(1024 + i) * nb + blk] = hs[i];
    }
}

// Scan phase A: 4096 elems/block partial sums.
__global__ void partial_kernel(const int* __restrict__ cnt, int* __restrict__ part, int m) {
    __shared__ int sm[256];
    int t = threadIdx.x;
    int base = blockIdx.x * 4096 + t * 16;
    int s = 0;
    if (base + 16 <= m) {
        const int4* p = (const int4*)(cnt + base);
        #pragma unroll
        for (int k = 0; k < 4; ++k) { int4 v = p[k]; s += v.x + v.y + v.z + v.w; }
    } else {
        for (int k = 0; k < 16; ++k) if (base + k < m) s += cnt[base + k];
    }
    sm[t] = s;
    __syncthreads();
    for (int st = 128; st > 0; st >>= 1) {
        if (t < st) sm[t] += sm[t + st];
        __syncthreads();
    }
    if (t == 0) part[blockIdx.x] = sm[0];
}

// Scan phase B: single-block exclusive scan of partials (nb <= 256).
__global__ void scan_part_kernel(int* __restrict__ part, int nb) {
    __shared__ int sm[256];
    int t = threadIdx.x;
    int v = (t < nb) ? part[t] : 0;
    sm[t] = v;
    __syncthreads();
    for (int d = 1; d < 256; d <<= 1) {
        int add = (t >= d) ? sm[t - d] : 0;
        __syncthreads();
        sm[t] += add;
        __syncthreads();
    }
    if (t < nb) part[t] = sm[t] - v;   // exclusive
}

// Scan phase C: exclusive scan -> Hoff[0..m).
__global__ void scan_final_kernel(const int* __restrict__ cnt, const int* __restrict__ part,
                                  int* __restrict__ Hoff, int m) {
    __shared__ int sm[256];
    int t = threadIdx.x;
    int base = blockIdx.x * 4096 + t * 16;
    int v[16];
    #pragma unroll
    for (int k = 0; k < 16; ++k) v[k] = (base + k < m) ? cnt[base + k] : 0;
    int s = 0;
    #pragma unroll
    for (int k = 0; k < 16; ++k) { int x = v[k]; v[k] = s; s += x; }
    sm[t] = s;
    __syncthreads();
    for (int d = 1; d < 256; d <<= 1) {
        int add = (t >= d) ? sm[t - d] : 0;
        __syncthreads();
        sm[t] += add;
        __syncthreads();
    }
    int tb = sm[t] - s + part[blockIdx.x];
    #pragma unroll
    for (int k = 0; k < 16; ++k)
        if (base + k < m) Hoff[base + k] = v[k] + tb;
}

// Scatter edges into 64-node range buckets (plain cached stores, LDS cursors).
// packed word = (src << 6) | (dst & 63); ksrc2 byte = src & 63.
__global__ __launch_bounds__(256) void bucket_scatter_kernel(
    const int* __restrict__ src, const int* __restrict__ dst,
    const int* __restrict__ Hoff,
    int* __restrict__ packed, unsigned char* __restrict__ ksrc2,
    int e, int nb) {
    __shared__ int dcur[1024], scur[1024];
    int t = threadIdx.x, blk = blockIdx.x;
    for (int i = t; i < 1024; i += 256) {
        dcur[i] = Hoff[i * nb + blk];
        scur[i] = Hoff[(1024 + i) * nb + blk] - e;   // src offsets live in [e,2e)
    }
    __syncthreads();
    int base = blk * TILE;
    #pragma unroll
    for (int s2 = 0; s2 < 16; ++s2) {
        int j = base + s2 * 256 + t;
        if (j < e) {
            int d = dst[j], sv = src[j];
            int pd = atomicAdd(&dcur[d >> 6], 1);
            packed[pd] = (sv << 6) | (d & 63);
            int ps = atomicAdd(&scur[sv >> 6], 1);
            ksrc2[ps] = (unsigned char)(sv & 63);
        }
    }
}

// One block per 64-node src range: LDS out-degree hist, then xs = x * rsqrt.
__global__ __launch_bounds__(256) void outdeg_prescale_kernel(
    const unsigned char* __restrict__ ksrc2, const int* __restrict__ Hoff,
    const float4* __restrict__ x4, float4* __restrict__ xs4,
    int n, int e, int nb) {
    __shared__ int lh[RB];
    int t = threadIdx.x, r = blockIdx.x;
    if (t < RB) lh[t] = 0;
    __syncthreads();
    int beg = Hoff[(1024 + r) * nb] - e;
    int end = Hoff[(1024 + r + 1) * nb] - e;
    for (int j = beg + t; j < end; j += 256)
        atomicAdd(&lh[ksrc2[j]], 1);
    __syncthreads();
    int base = r * RB;
    #pragma unroll
    for (int i = t; i < RB * 16; i += 256) {
        int row = i >> 4, g = base + row;
        if (g < n) {
            float s = rsqrtf((float)max(lh[row], 1));
            float4 v = x4[(long)g * 16 + (i & 15)];
            v.x *= s; v.y *= s; v.z *= s; v.w *= s;
            xs4[(long)g * 16 + (i & 15)] = v;
        }
    }
}

// One block per 64-node dst range: accumulate edges directly into LDS
// (ds_add_f32, bank-conflict-free: addr%32 == lane%32), count in-degree,
// write agg scaled by rsqrt(in_deg). No CSR needed.
__global__ __launch_bounds__(256) void mega_kernel(
    const int* __restrict__ packed, const int* __restrict__ Hoff,
    const float* __restrict__ xs, float4* __restrict__ agg4,
    int n, int e, int nb) {
    __shared__ float sAgg[RB * 64];
    __shared__ int cnt[RB];
    int t = threadIdx.x, r = blockIdx.x;
    int lane = t & 63, wid = t >> 6;
    for (int i = t; i < RB * 16; i += 256)
        ((float4*)sAgg)[i] = make_float4(0.f, 0.f, 0.f, 0.f);
    if (t < RB) cnt[t] = 0;
    __syncthreads();

    int beg = Hoff[r * nb];
    int end = Hoff[(r + 1) * nb];

    int j = beg + wid;
    for (; j + 12 < end; j += 16) {     // 4 edges/wave/iter, 8 loads in flight
        int p0 = packed[j];
        int p1 = packed[j + 4];
        int p2 = packed[j + 8];
        int p3 = packed[j + 12];
        float v0 = xs[(long)(p0 >> 6) * 64 + lane];
        float v1 = xs[(long)(p1 >> 6) * 64 + lane];
        float v2 = xs[(long)(p2 >> 6) * 64 + lane];
        float v3 = xs[(long)(p3 >> 6) * 64 + lane];
        atomicAdd(&sAgg[(p0 & 63) * 64 + lane], v0);
        atomicAdd(&sAgg[(p1 & 63) * 64 + lane], v1);
        atomicAdd(&sAgg[(p2 & 63) * 64 + lane], v2);
        atomicAdd(&sAgg[(p3 & 63) * 64 + lane], v3);
        if (lane == 0) {
            atomicAdd(&cnt[p0 & 63], 1);
            atomicAdd(&cnt[p1 & 63], 1);
            atomicAdd(&cnt[p2 & 63], 1);
            atomicAdd(&cnt[p3 & 63], 1);
        }
    }
    for (; j < end; j += 4) {
        int p = packed[j];
        float v = xs[(long)(p >> 6) * 64 + lane];
        atomicAdd(&sAgg[(p & 63) * 64 + lane], v);
        if (lane == 0) atomicAdd(&cnt[p & 63], 1);
    }
    __syncthreads();

    int base = r * RB;
    #pragma unroll
    for (int i = t; i < RB * 16; i += 256) {
        int row = i >> 4, g = base + row;
        if (g < n) {
            float nd = rsqrtf((float)max(cnt[row], 1));
            float4 v = ((const float4*)sAgg)[i];
            v.x *= nd; v.y *= nd; v.z *= nd; v.w *= nd;
            agg4[(long)g * 16 + (i & 15)] = v;
        }
    }
}

// out[r][c] = agg[r][:]@W[:,c] + x[r][:]@Wr[:,c] + (b+br)[c]
// Lane c holds W[:,c], Wr[:,c] in VGPRs (static unroll); rows staged in LDS.
#define OR 32
__global__ __launch_bounds__(256) void out_kernel(
    const float4* __restrict__ agg4, const float4* __restrict__ x4,
    const float* __restrict__ W, const float* __restrict__ b,
    const float* __restrict__ Wr, const float* __restrict__ br,
    float* __restrict__ out, int n) {
    __shared__ float4 sA[OR * 16];
    __shared__ float4 sX[OR * 16];
    int t = threadIdx.x;
    int c = t & 63;
    int base = blockIdx.x * OR;

    float4 wA[16], wR[16];
    #pragma unroll
    for (int q = 0; q < 16; ++q) {
        wA[q].x = W[(4 * q + 0) * 64 + c];
        wA[q].y = W[(4 * q + 1) * 64 + c];
        wA[q].z = W[(4 * q + 2) * 64 + c];
        wA[q].w = W[(4 * q + 3) * 64 + c];
        wR[q].x = Wr[(4 * q + 0) * 64 + c];
        wR[q].y = Wr[(4 * q + 1) * 64 + c];
        wR[q].z = Wr[(4 * q + 2) * 64 + c];
        wR[q].w = Wr[(4 * q + 3) * 64 + c];
    }

    #pragma unroll
    for (int i = 0; i < 2; ++i) {          // stage 32 rows of A and X
        int qi = t + 256 * i;              // 0..511
        int row = base + (qi >> 4);
        float4 z = make_float4(0.f, 0.f, 0.f, 0.f);
        sA[qi] = (row < n) ? agg4[(long)row * 16 + (qi & 15)] : z;
        sX[qi] = (row < n) ? x4[(long)row * 16 + (qi & 15)] : z;
    }
    __syncthreads();

    int w = t >> 6;
    float bias = b[c] + br[c];
    for (int r = w * 8; r < w * 8 + 8; ++r) {
        float a0 = 0.f, a1 = 0.f, r0 = 0.f, r1 = 0.f;
        #pragma unroll
        for (int q = 0; q < 16; q += 2) {
            float4 av0 = sA[r * 16 + q];
            float4 av1 = sA[r * 16 + q + 1];
            float4 xv0 = sX[r * 16 + q];
            float4 xv1 = sX[r * 16 + q + 1];
            a0 += av0.x * wA[q].x + av0.y * wA[q].y + av0.z * wA[q].z + av0.w * wA[q].w;
            a1 += av1.x * wA[q + 1].x + av1.y * wA[q + 1].y + av1.z * wA[q + 1].z + av1.w * wA[q + 1].w;
            r0 += xv0.x * wR[q].x + xv0.y * wR[q].y + xv0.z * wR[q].z + xv0.w * wR[q].w;
            r1 += xv1.x * wR[q + 1].x + xv1.y * wR[q + 1].y + xv1.z * wR[q + 1].z + xv1.w * wR[q + 1].w;
        }
        int grow = base + r;
        if (grow < n) out[(long)grow * 64 + c] = (a0 + a1) + (r0 + r1) + bias;
    }
}

extern "C" void kernel_launch(void* const* d_in, const int* in_sizes, int n_in,
                              void* d_out, int out_size, void* d_ws, size_t ws_size,
                              hipStream_t stream) {
    const float* x   = (const float*)d_in[0];
    const int*   src = (const int*)d_in[1];
    const int*   dst = (const int*)d_in[2];
    const float* W   = (const float*)d_in[3];
    const float* b   = (const float*)d_in[4];
    const float* Wr  = (const float*)d_in[5];
    const float* br  = (const float*)d_in[6];
    float* out = (float*)d_out;

    const int n = in_sizes[0] / 64;            // 50000
    const int e = in_sizes[1];                 // 800000
    const int nb = (e + TILE - 1) / TILE;      // 196 bucket blocks
    const int nrange = (n + RB - 1) / RB;      // 782 node ranges
    const int m = 2 * 1024 * nb;               // 401408 hist entries
    const int nbs = (m + 4095) / 4096;         // 98 scan blocks

    int*   H      = (int*)d_ws;                // m
    int*   Hoff   = H + m;                     // m
    int*   part   = Hoff + m;                  // 256
    int*   packed = part + 256;                // e
    float* xs     = (float*)(packed + e);      // n*64  (16B aligned)
    float* agg    = xs + (size_t)n * 64;       // n*64
    unsigned char* ksrc2 = (unsigned char*)(agg + (size_t)n * 64); // e bytes

    bucket_hist_kernel<<<nb, 256, 0, stream>>>(src, dst, H, e, nb);

    partial_kernel<<<nbs, 256, 0, stream>>>(H, part, m);
    scan_part_kernel<<<1, 256, 0, stream>>>(part, nbs);
    scan_final_kernel<<<nbs, 256, 0, stream>>>(H, part, Hoff, m);

    bucket_scatter_kernel<<<nb, 256, 0, stream>>>(src, dst, Hoff, packed, ksrc2, e, nb);

    outdeg_prescale_kernel<<<nrange, 256, 0, stream>>>(
        ksrc2, Hoff, (const float4*)x, (float4*)xs, n, e, nb);

    mega_kernel<<<nrange, 256, 0, stream>>>(packed, Hoff, xs, (float4*)agg, n, e, nb);

    out_kernel<<<(n + OR - 1) / OR, 256, 0, stream>>>(
        (const float4*)agg, (const float4*)x, W, b, Wr, br, out, n);
}

// Round 11
// 128.480 us; speedup vs baseline: 3.3277x; 3.3277x over previous
//
#include <hip/hip_runtime.h>

// ---------------------------------------------------------------------------
// GraphConv (DGL norm='both') + residual linear:
//   out = (D_dst^-1/2 * A^T * (D_src^-1/2 * x)) @ W + x @ Wr + (b + br)
// Round 11: R9 structure (atomic-free CSR build via 256-node range buckets)
// + packed edge words, fused outdeg+prescale, deeper gather unroll.
// ---------------------------------------------------------------------------

#define TILE 4096   // edges per bucket block

// Per-block LDS histograms of dst>>8 and src>>8.
// H layout: H[bin*nb + blk] (dst), H[256*nb + bin*nb + blk] (src).
__global__ __launch_bounds__(256) void bucket_hist_kernel(
    const int* __restrict__ src, const int* __restrict__ dst,
    int* __restrict__ H, int e, int nb) {
    __shared__ int hd[256], hs[256];
    int t = threadIdx.x, blk = blockIdx.x;
    hd[t] = 0; hs[t] = 0;
    __syncthreads();
    int base = blk * TILE;
    #pragma unroll
    for (int s = 0; s < 16; ++s) {
        int j = base + s * 256 + t;
        if (j < e) {
            atomicAdd(&hd[dst[j] >> 8], 1);
            atomicAdd(&hs[src[j] >> 8], 1);
        }
    }
    __syncthreads();
    H[t * nb + blk]            = hd[t];
    H[256 * nb + t * nb + blk] = hs[t];
}

// Scan phase A: 4096 elems/block partial sums.
__global__ void partial_kernel(const int* __restrict__ cnt, int* __restrict__ part, int m) {
    __shared__ int sm[256];
    int t = threadIdx.x;
    int base = blockIdx.x * 4096 + t * 16;
    int s = 0;
    if (base + 16 <= m) {
        const int4* p = (const int4*)(cnt + base);
        #pragma unroll
        for (int k = 0; k < 4; ++k) { int4 v = p[k]; s += v.x + v.y + v.z + v.w; }
    } else {
        for (int k = 0; k < 16; ++k) if (base + k < m) s += cnt[base + k];
    }
    sm[t] = s;
    __syncthreads();
    for (int st = 128; st > 0; st >>= 1) {
        if (t < st) sm[t] += sm[t + st];
        __syncthreads();
    }
    if (t == 0) part[blockIdx.x] = sm[0];
}

// Scan phase B: single-block exclusive scan of partials (nb <= 256).
__global__ void scan_part_kernel(int* __restrict__ part, int nb) {
    __shared__ int sm[256];
    int t = threadIdx.x;
    int v = (t < nb) ? part[t] : 0;
    sm[t] = v;
    __syncthreads();
    for (int d = 1; d < 256; d <<= 1) {
        int add = (t >= d) ? sm[t - d] : 0;
        __syncthreads();
        sm[t] += add;
        __syncthreads();
    }
    if (t < nb) part[t] = sm[t] - v;   // exclusive
}

// Scan phase C: exclusive scan -> Hoff[0..m).
__global__ void scan_final_kernel(const int* __restrict__ cnt, const int* __restrict__ part,
                                  int* __restrict__ Hoff, int m) {
    __shared__ int sm[256];
    int t = threadIdx.x;
    int base = blockIdx.x * 4096 + t * 16;
    int v[16];
    #pragma unroll
    for (int k = 0; k < 16; ++k) v[k] = (base + k < m) ? cnt[base + k] : 0;
    int s = 0;
    #pragma unroll
    for (int k = 0; k < 16; ++k) { int x = v[k]; v[k] = s; s += x; }
    sm[t] = s;
    __syncthreads();
    for (int d = 1; d < 256; d <<= 1) {
        int add = (t >= d) ? sm[t - d] : 0;
        __syncthreads();
        sm[t] += add;
        __syncthreads();
    }
    int tb = sm[t] - s + part[blockIdx.x];
    #pragma unroll
    for (int k = 0; k < 16; ++k)
        if (base + k < m) Hoff[base + k] = v[k] + tb;
}

// Scatter edges into range buckets. packed = (src<<8)|(dst&255) into dst
// buckets; 1-byte (src&255) into src buckets. LDS cursors, cached stores.
__global__ __launch_bounds__(256) void bucket_scatter_kernel(
    const int* __restrict__ src, const int* __restrict__ dst,
    const int* __restrict__ Hoff,
    int* __restrict__ packed, unsigned char* __restrict__ ksrc2,
    int e, int nb) {
    __shared__ int dcur[256], scur[256];
    int t = threadIdx.x, blk = blockIdx.x;
    dcur[t] = Hoff[t * nb + blk];
    scur[t] = Hoff[256 * nb + t * nb + blk] - e;   // src offsets live in [e,2e)
    __syncthreads();
    int base = blk * TILE;
    #pragma unroll
    for (int s2 = 0; s2 < 16; ++s2) {
        int j = base + s2 * 256 + t;
        if (j < e) {
            int d = dst[j], sv = src[j];
            int pd = atomicAdd(&dcur[d >> 8], 1);
            packed[pd] = (sv << 8) | (d & 255);
            int ps = atomicAdd(&scur[sv >> 8], 1);
            ksrc2[ps] = (unsigned char)(sv & 255);
        }
    }
}

// One block per 256-node range: LDS hist -> LDS scan -> roff + col.
__global__ __launch_bounds__(256) void csr_kernel(
    const int* __restrict__ packed, const int* __restrict__ Hoff,
    int* __restrict__ roff, int* __restrict__ col,
    int n, int e, int nb, int nrange) {
    __shared__ int lh[256], sm[256];
    int t = threadIdx.x, r = blockIdx.x;
    int beg = Hoff[r * nb];
    int end = (r + 1 < nrange) ? Hoff[(r + 1) * nb] : e;
    lh[t] = 0;
    __syncthreads();
    for (int j = beg + t; j < end; j += 256)
        atomicAdd(&lh[packed[j] & 255], 1);
    __syncthreads();
    int v0 = lh[t];
    sm[t] = v0;
    __syncthreads();
    for (int d = 1; d < 256; d <<= 1) {
        int add = (t >= d) ? sm[t - d] : 0;
        __syncthreads();
        sm[t] += add;
        __syncthreads();
    }
    int excl = sm[t] - v0;
    int v = r * 256 + t;
    if (v < n) roff[v] = beg + excl;
    __syncthreads();          // all v0 reads done before lh reuse
    lh[t] = excl;             // lh becomes the local cursor array
    __syncthreads();
    for (int j = beg + t; j < end; j += 256) {
        int p = packed[j];
        int pos = beg + atomicAdd(&lh[p & 255], 1);
        col[pos] = p >> 8;
    }
    if (r == 0 && t == 0) roff[n] = e;
}

// One block per 256-node src range: LDS out-degree hist, then xs = x * rsqrt.
__global__ __launch_bounds__(256) void outdeg_prescale_kernel(
    const unsigned char* __restrict__ ksrc2, const int* __restrict__ Hoff,
    const float4* __restrict__ x4, float4* __restrict__ xs4,
    int n, int e, int nb, int nrange) {
    __shared__ int lh[256];
    int t = threadIdx.x, r = blockIdx.x;
    lh[t] = 0;
    __syncthreads();
    int beg = Hoff[256 * nb + r * nb] - e;
    int end = (r + 1 < nrange) ? (Hoff[256 * nb + (r + 1) * nb] - e) : e;
    for (int j = beg + t; j < end; j += 256)
        atomicAdd(&lh[ksrc2[j]], 1);
    __syncthreads();
    int base = r * 256;
    for (int i = t; i < 256 * 16; i += 256) {
        int row = i >> 4, g = base + row;
        if (g < n) {
            float s = rsqrtf((float)max(lh[row], 1));
            float4 v = x4[(long)g * 16 + (i & 15)];
            v.x *= s; v.y *= s; v.z *= s; v.w *= s;
            xs4[(long)g * 16 + (i & 15)] = v;
        }
    }
}

// One wave per node. Lane = (edge-slot g = lane>>4) x (feature-quad q = lane&15).
// agg[node] = rsqrt(max(in_deg,1)) * sum_{s in N(node)} xs[s].
__global__ __launch_bounds__(256) void gather_kernel(
    const float4* __restrict__ xs4, const int* __restrict__ col,
    const int* __restrict__ roff,
    float4* __restrict__ agg4, int n) {
    int lane = threadIdx.x & 63;
    int node = (blockIdx.x * 256 + threadIdx.x) >> 6;
    if (node >= n) return;
    node = __builtin_amdgcn_readfirstlane(node);   // wave-uniform -> scalar loads

    int beg = roff[node];
    int end = roff[node + 1];
    int g = lane >> 4;   // edge sub-slot 0..3
    int q = lane & 15;   // feature quad 0..15

    float4 acc = make_float4(0.f, 0.f, 0.f, 0.f);
    int j = beg;
    for (; j + 16 <= end; j += 16) {        // 16 edges: 4 x 16B loads in flight
        int s0 = col[j + g];
        int s1 = col[j + 4 + g];
        int s2 = col[j + 8 + g];
        int s3 = col[j + 12 + g];
        float4 v0 = xs4[(long)s0 * 16 + q];
        float4 v1 = xs4[(long)s1 * 16 + q];
        float4 v2 = xs4[(long)s2 * 16 + q];
        float4 v3 = xs4[(long)s3 * 16 + q];
        acc.x += (v0.x + v1.x) + (v2.x + v3.x);
        acc.y += (v0.y + v1.y) + (v2.y + v3.y);
        acc.z += (v0.z + v1.z) + (v2.z + v3.z);
        acc.w += (v0.w + v1.w) + (v2.w + v3.w);
    }
    for (; j + 8 <= end; j += 8) {
        int s0 = col[j + g];
        int s1 = col[j + 4 + g];
        float4 v0 = xs4[(long)s0 * 16 + q];
        float4 v1 = xs4[(long)s1 * 16 + q];
        acc.x += v0.x + v1.x;
        acc.y += v0.y + v1.y;
        acc.z += v0.z + v1.z;
        acc.w += v0.w + v1.w;
    }
    for (; j < end; j += 4) {               // predicated 4-edge tail
        int jj = j + g;
        int s   = (jj < end) ? col[jj] : node;   // safe dummy index
        float m = (jj < end) ? 1.f : 0.f;
        float4 v = xs4[(long)s * 16 + q];
        acc.x += v.x * m;
        acc.y += v.y * m;
        acc.z += v.z * m;
        acc.w += v.w * m;
    }

    acc.x += __shfl_down(acc.x, 32);
    acc.y += __shfl_down(acc.y, 32);
    acc.z += __shfl_down(acc.z, 32);
    acc.w += __shfl_down(acc.w, 32);
    acc.x += __shfl_down(acc.x, 16);
    acc.y += __shfl_down(acc.y, 16);
    acc.z += __shfl_down(acc.z, 16);
    acc.w += __shfl_down(acc.w, 16);

    float nd = rsqrtf((float)max(end - beg, 1));
    if (lane < 16) {
        acc.x *= nd; acc.y *= nd; acc.z *= nd; acc.w *= nd;
        agg4[(long)node * 16 + q] = acc;
    }
}

// out[r][c] = agg[r][:]@W[:,c] + x[r][:]@Wr[:,c] + (b+br)[c]
// Lane c holds W[:,c], Wr[:,c] in VGPRs (static unroll); rows staged in LDS.
#define OR 32
__global__ __launch_bounds__(256) void out_kernel(
    const float4* __restrict__ agg4, const float4* __restrict__ x4,
    const float* __restrict__ W, const float* __restrict__ b,
    const float* __restrict__ Wr, const float* __restrict__ br,
    float* __restrict__ out, int n) {
    __shared__ float4 sA[OR * 16];
    __shared__ float4 sX[OR * 16];
    int t = threadIdx.x;
    int c = t & 63;
    int base = blockIdx.x * OR;

    float4 wA[16], wR[16];
    #pragma unroll
    for (int q = 0; q < 16; ++q) {
        wA[q].x = W[(4 * q + 0) * 64 + c];
        wA[q].y = W[(4 * q + 1) * 64 + c];
        wA[q].z = W[(4 * q + 2) * 64 + c];
        wA[q].w = W[(4 * q + 3) * 64 + c];
        wR[q].x = Wr[(4 * q + 0) * 64 + c];
        wR[q].y = Wr[(4 * q + 1) * 64 + c];
        wR[q].z = Wr[(4 * q + 2) * 64 + c];
        wR[q].w = Wr[(4 * q + 3) * 64 + c];
    }

    #pragma unroll
    for (int i = 0; i < 2; ++i) {          // stage 32 rows of A and X
        int qi = t + 256 * i;              // 0..511
        int row = base + (qi >> 4);
        float4 z = make_float4(0.f, 0.f, 0.f, 0.f);
        sA[qi] = (row < n) ? agg4[(long)row * 16 + (qi & 15)] : z;
        sX[qi] = (row < n) ? x4[(long)row * 16 + (qi & 15)] : z;
    }
    __syncthreads();

    int w = t >> 6;
    float bias = b[c] + br[c];
    for (int r = w * 8; r < w * 8 + 8; ++r) {
        float a0 = 0.f, a1 = 0.f, r0 = 0.f, r1 = 0.f;
        #pragma unroll
        for (int q = 0; q < 16; q += 2) {
            float4 av0 = sA[r * 16 + q];
            float4 av1 = sA[r * 16 + q + 1];
            float4 xv0 = sX[r * 16 + q];
            float4 xv1 = sX[r * 16 + q + 1];
            a0 += av0.x * wA[q].x + av0.y * wA[q].y + av0.z * wA[q].z + av0.w * wA[q].w;
            a1 += av1.x * wA[q + 1].x + av1.y * wA[q + 1].y + av1.z * wA[q + 1].z + av1.w * wA[q + 1].w;
            r0 += xv0.x * wR[q].x + xv0.y * wR[q].y + xv0.z * wR[q].z + xv0.w * wR[q].w;
            r1 += xv1.x * wR[q + 1].x + xv1.y * wR[q + 1].y + xv1.z * wR[q + 1].z + xv1.w * wR[q + 1].w;
        }
        int grow = base + r;
        if (grow < n) out[(long)grow * 64 + c] = (a0 + a1) + (r0 + r1) + bias;
    }
}

extern "C" void kernel_launch(void* const* d_in, const int* in_sizes, int n_in,
                              void* d_out, int out_size, void* d_ws, size_t ws_size,
                              hipStream_t stream) {
    const float* x   = (const float*)d_in[0];
    const int*   src = (const int*)d_in[1];
    const int*   dst = (const int*)d_in[2];
    const float* W   = (const float*)d_in[3];
    const float* b   = (const float*)d_in[4];
    const float* Wr  = (const float*)d_in[5];
    const float* br  = (const float*)d_in[6];
    float* out = (float*)d_out;

    const int n = in_sizes[0] / 64;            // 50000
    const int e = in_sizes[1];                 // 800000
    const int nb = (e + TILE - 1) / TILE;      // 196 bucket blocks
    const int nrange = (n + 255) / 256;        // 196 node ranges
    const int m = 2 * 256 * nb;                // 100352 hist entries
    const int nbs = (m + 4095) / 4096;         // 25 scan blocks

    int*   H      = (int*)d_ws;                // m
    int*   Hoff   = H + m;                     // m
    int*   part   = Hoff + m;                  // 256
    int*   packed = part + 256;                // e
    int*   roff   = packed + e;                // n+1
    int*   col    = roff + n + 1;              // e
    float* xs     = (float*)(col + e);         // n*64
    float* agg    = xs + (size_t)n * 64;       // n*64
    unsigned char* ksrc2 = (unsigned char*)(agg + (size_t)n * 64); // e bytes

    bucket_hist_kernel<<<nb, 256, 0, stream>>>(src, dst, H, e, nb);

    partial_kernel<<<nbs, 256, 0, stream>>>(H, part, m);
    scan_part_kernel<<<1, 256, 0, stream>>>(part, nbs);
    scan_final_kernel<<<nbs, 256, 0, stream>>>(H, part, Hoff, m);

    bucket_scatter_kernel<<<nb, 256, 0, stream>>>(src, dst, Hoff, packed, ksrc2, e, nb);

    csr_kernel<<<nrange, 256, 0, stream>>>(packed, Hoff, roff, col, n, e, nb, nrange);

    outdeg_prescale_kernel<<<nrange, 256, 0, stream>>>(
        ksrc2, Hoff, (const float4*)x, (float4*)xs, n, e, nb, nrange);

    gather_kernel<<<(n * 64 + 255) / 256, 256, 0, stream>>>(
        (const float4*)xs, col, roff, (float4*)agg, n);

    out_kernel<<<(n + OR - 1) / OR, 256, 0, stream>>>(
        (const float4*)agg, (const float4*)x, W, b, Wr, br, out, n);
}

// Round 12
// 117.815 us; speedup vs baseline: 3.6289x; 1.0905x over previous
//
#include <hip/hip_runtime.h>

// ---------------------------------------------------------------------------
// GraphConv (DGL norm='both') + residual linear:
//   out = (D_dst^-1/2 * A^T * (D_src^-1/2 * x)) @ W + x @ Wr + (b + br)
// Round 12: consolidation. 7 launches: hist -> partial -> scan(final, self-
// scans partials) -> scatter -> [csr || outdeg+prescale fused grid] ->
// gather -> out. Zero global atomics.
// ---------------------------------------------------------------------------

#define TILE 4096   // edges per bucket block

// Per-block LDS histograms of dst>>8 and src>>8.
// H layout: H[bin*nb + blk] (dst), H[256*nb + bin*nb + blk] (src).
__global__ __launch_bounds__(256) void bucket_hist_kernel(
    const int* __restrict__ src, const int* __restrict__ dst,
    int* __restrict__ H, int e, int nb) {
    __shared__ int hd[256], hs[256];
    int t = threadIdx.x, blk = blockIdx.x;
    hd[t] = 0; hs[t] = 0;
    __syncthreads();
    int base = blk * TILE;
    #pragma unroll
    for (int s = 0; s < 16; ++s) {
        int j = base + s * 256 + t;
        if (j < e) {
            atomicAdd(&hd[dst[j] >> 8], 1);
            atomicAdd(&hs[src[j] >> 8], 1);
        }
    }
    __syncthreads();
    H[t * nb + blk]            = hd[t];
    H[256 * nb + t * nb + blk] = hs[t];
}

// Scan phase A: 4096 elems/block partial sums.
__global__ void partial_kernel(const int* __restrict__ cnt, int* __restrict__ part, int m) {
    __shared__ int sm[256];
    int t = threadIdx.x;
    int base = blockIdx.x * 4096 + t * 16;
    int s = 0;
    if (base + 16 <= m) {
        const int4* p = (const int4*)(cnt + base);
        #pragma unroll
        for (int k = 0; k < 4; ++k) { int4 v = p[k]; s += v.x + v.y + v.z + v.w; }
    } else {
        for (int k = 0; k < 16; ++k) if (base + k < m) s += cnt[base + k];
    }
    sm[t] = s;
    __syncthreads();
    for (int st = 128; st > 0; st >>= 1) {
        if (t < st) sm[t] += sm[t + st];
        __syncthreads();
    }
    if (t == 0) part[blockIdx.x] = sm[0];
}

// Scan phase B+C fused: each block redundantly exclusive-scans the (<=256)
// partials in LDS, then does its local 4096-elem exclusive scan -> Hoff.
__global__ void scan_final_kernel(const int* __restrict__ cnt, const int* __restrict__ part,
                                  int* __restrict__ Hoff, int m, int nbs) {
    __shared__ int sm[256], sp[256];
    int t = threadIdx.x;
    // scan the partials
    int pv = (t < nbs) ? part[t] : 0;
    sp[t] = pv;
    __syncthreads();
    for (int d = 1; d < 256; d <<= 1) {
        int add = (t >= d) ? sp[t - d] : 0;
        __syncthreads();
        sp[t] += add;
        __syncthreads();
    }
    sp[t] -= pv;   // exclusive
    __syncthreads();
    int blkoff = sp[blockIdx.x];

    int base = blockIdx.x * 4096 + t * 16;
    int v[16];
    #pragma unroll
    for (int k = 0; k < 16; ++k) v[k] = (base + k < m) ? cnt[base + k] : 0;
    int s = 0;
    #pragma unroll
    for (int k = 0; k < 16; ++k) { int x = v[k]; v[k] = s; s += x; }
    sm[t] = s;
    __syncthreads();
    for (int d = 1; d < 256; d <<= 1) {
        int add = (t >= d) ? sm[t - d] : 0;
        __syncthreads();
        sm[t] += add;
        __syncthreads();
    }
    int tb = sm[t] - s + blkoff;
    #pragma unroll
    for (int k = 0; k < 16; ++k)
        if (base + k < m) Hoff[base + k] = v[k] + tb;
}

// Scatter edges into range buckets. packed = (src<<8)|(dst&255) into dst
// buckets; 1-byte (src&255) into src buckets. LDS cursors, cached stores.
__global__ __launch_bounds__(256) void bucket_scatter_kernel(
    const int* __restrict__ src, const int* __restrict__ dst,
    const int* __restrict__ Hoff,
    int* __restrict__ packed, unsigned char* __restrict__ ksrc2,
    int e, int nb) {
    __shared__ int dcur[256], scur[256];
    int t = threadIdx.x, blk = blockIdx.x;
    dcur[t] = Hoff[t * nb + blk];
    scur[t] = Hoff[256 * nb + t * nb + blk] - e;   // src offsets live in [e,2e)
    __syncthreads();
    int base = blk * TILE;
    #pragma unroll
    for (int s2 = 0; s2 < 16; ++s2) {
        int j = base + s2 * 256 + t;
        if (j < e) {
            int d = dst[j], sv = src[j];
            int pd = atomicAdd(&dcur[d >> 8], 1);
            packed[pd] = (sv << 8) | (d & 255);
            int ps = atomicAdd(&scur[sv >> 8], 1);
            ksrc2[ps] = (unsigned char)(sv & 255);
        }
    }
}

// Fused grid: blocks [0,nrange) build CSR (roff+col) for their 256-node dst
// range; blocks [nrange,2*nrange) compute out-degree + prescale xs for their
// 256-node src range. Independent stages -> concurrent occupancy.
__global__ __launch_bounds__(256) void csr_outdeg_kernel(
    const int* __restrict__ packed, const unsigned char* __restrict__ ksrc2,
    const int* __restrict__ Hoff,
    int* __restrict__ roff, int* __restrict__ col,
    const float4* __restrict__ x4, float4* __restrict__ xs4,
    int n, int e, int nb, int nrange) {
    __shared__ int lh[256], sm[256];
    int t = threadIdx.x;
    int r = blockIdx.x;
    if (r < nrange) {
        // ---- CSR build for dst range r ----
        int beg = Hoff[r * nb];
        int end = (r + 1 < nrange) ? Hoff[(r + 1) * nb] : e;
        lh[t] = 0;
        __syncthreads();
        for (int j = beg + t; j < end; j += 256)
            atomicAdd(&lh[packed[j] & 255], 1);
        __syncthreads();
        int v0 = lh[t];
        sm[t] = v0;
        __syncthreads();
        for (int d = 1; d < 256; d <<= 1) {
            int add = (t >= d) ? sm[t - d] : 0;
            __syncthreads();
            sm[t] += add;
            __syncthreads();
        }
        int excl = sm[t] - v0;
        int v = r * 256 + t;
        if (v < n) roff[v] = beg + excl;
        __syncthreads();          // all v0 reads done before lh reuse
        lh[t] = excl;             // lh becomes the local cursor array
        __syncthreads();
        for (int j = beg + t; j < end; j += 256) {
            int p = packed[j];
            int pos = beg + atomicAdd(&lh[p & 255], 1);
            col[pos] = p >> 8;
        }
        if (r == 0 && t == 0) roff[n] = e;
    } else {
        // ---- out-degree + prescale for src range r-nrange ----
        r -= nrange;
        lh[t] = 0;
        __syncthreads();
        int beg = Hoff[256 * nb + r * nb] - e;
        int end = (r + 1 < nrange) ? (Hoff[256 * nb + (r + 1) * nb] - e) : e;
        for (int j = beg + t; j < end; j += 256)
            atomicAdd(&lh[ksrc2[j]], 1);
        __syncthreads();
        int base = r * 256;
        for (int i = t; i < 256 * 16; i += 256) {
            int row = i >> 4, g = base + row;
            if (g < n) {
                float s = rsqrtf((float)max(lh[row], 1));
                float4 v = x4[(long)g * 16 + (i & 15)];
                v.x *= s; v.y *= s; v.z *= s; v.w *= s;
                xs4[(long)g * 16 + (i & 15)] = v;
            }
        }
    }
}

// One wave per node. Lane = (edge-slot g = lane>>4) x (feature-quad q = lane&15).
// agg[node] = rsqrt(max(in_deg,1)) * sum_{s in N(node)} xs[s].
__global__ __launch_bounds__(256) void gather_kernel(
    const float4* __restrict__ xs4, const int* __restrict__ col,
    const int* __restrict__ roff,
    float4* __restrict__ agg4, int n) {
    int lane = threadIdx.x & 63;
    int node = (blockIdx.x * 256 + threadIdx.x) >> 6;
    if (node >= n) return;
    node = __builtin_amdgcn_readfirstlane(node);   // wave-uniform -> scalar loads

    int beg = roff[node];
    int end = roff[node + 1];
    int g = lane >> 4;   // edge sub-slot 0..3
    int q = lane & 15;   // feature quad 0..15

    float4 acc = make_float4(0.f, 0.f, 0.f, 0.f);
    int j = beg;
    for (; j + 16 <= end; j += 16) {        // 16 edges: 4 x 16B loads in flight
        int s0 = col[j + g];
        int s1 = col[j + 4 + g];
        int s2 = col[j + 8 + g];
        int s3 = col[j + 12 + g];
        float4 v0 = xs4[(long)s0 * 16 + q];
        float4 v1 = xs4[(long)s1 * 16 + q];
        float4 v2 = xs4[(long)s2 * 16 + q];
        float4 v3 = xs4[(long)s3 * 16 + q];
        acc.x += (v0.x + v1.x) + (v2.x + v3.x);
        acc.y += (v0.y + v1.y) + (v2.y + v3.y);
        acc.z += (v0.z + v1.z) + (v2.z + v3.z);
        acc.w += (v0.w + v1.w) + (v2.w + v3.w);
    }
    for (; j + 8 <= end; j += 8) {
        int s0 = col[j + g];
        int s1 = col[j + 4 + g];
        float4 v0 = xs4[(long)s0 * 16 + q];
        float4 v1 = xs4[(long)s1 * 16 + q];
        acc.x += v0.x + v1.x;
        acc.y += v0.y + v1.y;
        acc.z += v0.z + v1.z;
        acc.w += v0.w + v1.w;
    }
    for (; j < end; j += 4) {               // predicated 4-edge tail
        int jj = j + g;
        int s   = (jj < end) ? col[jj] : node;   // safe dummy index
        float m = (jj < end) ? 1.f : 0.f;
        float4 v = xs4[(long)s * 16 + q];
        acc.x += v.x * m;
        acc.y += v.y * m;
        acc.z += v.z * m;
        acc.w += v.w * m;
    }

    acc.x += __shfl_down(acc.x, 32);
    acc.y += __shfl_down(acc.y, 32);
    acc.z += __shfl_down(acc.z, 32);
    acc.w += __shfl_down(acc.w, 32);
    acc.x += __shfl_down(acc.x, 16);
    acc.y += __shfl_down(acc.y, 16);
    acc.z += __shfl_down(acc.z, 16);
    acc.w += __shfl_down(acc.w, 16);

    float nd = rsqrtf((float)max(end - beg, 1));
    if (lane < 16) {
        acc.x *= nd; acc.y *= nd; acc.z *= nd; acc.w *= nd;
        agg4[(long)node * 16 + q] = acc;
    }
}

// out[r][c] = agg[r][:]@W[:,c] + x[r][:]@Wr[:,c] + (b+br)[c]
// Lane c holds W[:,c], Wr[:,c] in VGPRs (static unroll); rows staged in LDS.
#define OR 32
__global__ __launch_bounds__(256) void out_kernel(
    const float4* __restrict__ agg4, const float4* __restrict__ x4,
    const float* __restrict__ W, const float* __restrict__ b,
    const float* __restrict__ Wr, const float* __restrict__ br,
    float* __restrict__ out, int n) {
    __shared__ float4 sA[OR * 16];
    __shared__ float4 sX[OR * 16];
    int t = threadIdx.x;
    int c = t & 63;
    int base = blockIdx.x * OR;

    float4 wA[16], wR[16];
    #pragma unroll
    for (int q = 0; q < 16; ++q) {
        wA[q].x = W[(4 * q + 0) * 64 + c];
        wA[q].y = W[(4 * q + 1) * 64 + c];
        wA[q].z = W[(4 * q + 2) * 64 + c];
        wA[q].w = W[(4 * q + 3) * 64 + c];
        wR[q].x = Wr[(4 * q + 0) * 64 + c];
        wR[q].y = Wr[(4 * q + 1) * 64 + c];
        wR[q].z = Wr[(4 * q + 2) * 64 + c];
        wR[q].w = Wr[(4 * q + 3) * 64 + c];
    }

    #pragma unroll
    for (int i = 0; i < 2; ++i) {          // stage 32 rows of A and X
        int qi = t + 256 * i;              // 0..511
        int row = base + (qi >> 4);
        float4 z = make_float4(0.f, 0.f, 0.f, 0.f);
        sA[qi] = (row < n) ? agg4[(long)row * 16 + (qi & 15)] : z;
        sX[qi] = (row < n) ? x4[(long)row * 16 + (qi & 15)] : z;
    }
    __syncthreads();

    int w = t >> 6;
    float bias = b[c] + br[c];
    for (int r = w * 8; r < w * 8 + 8; ++r) {
        float a0 = 0.f, a1 = 0.f, r0 = 0.f, r1 = 0.f;
        #pragma unroll
        for (int q = 0; q < 16; q += 2) {
            float4 av0 = sA[r * 16 + q];
            float4 av1 = sA[r * 16 + q + 1];
            float4 xv0 = sX[r * 16 + q];
            float4 xv1 = sX[r * 16 + q + 1];
            a0 += av0.x * wA[q].x + av0.y * wA[q].y + av0.z * wA[q].z + av0.w * wA[q].w;
            a1 += av1.x * wA[q + 1].x + av1.y * wA[q + 1].y + av1.z * wA[q + 1].z + av1.w * wA[q + 1].w;
            r0 += xv0.x * wR[q].x + xv0.y * wR[q].y + xv0.z * wR[q].z + xv0.w * wR[q].w;
            r1 += xv1.x * wR[q + 1].x + xv1.y * wR[q + 1].y + xv1.z * wR[q + 1].z + xv1.w * wR[q + 1].w;
        }
        int grow = base + r;
        if (grow < n) out[(long)grow * 64 + c] = (a0 + a1) + (r0 + r1) + bias;
    }
}

extern "C" void kernel_launch(void* const* d_in, const int* in_sizes, int n_in,
                              void* d_out, int out_size, void* d_ws, size_t ws_size,
                              hipStream_t stream) {
    const float* x   = (const float*)d_in[0];
    const int*   src = (const int*)d_in[1];
    const int*   dst = (const int*)d_in[2];
    const float* W   = (const float*)d_in[3];
    const float* b   = (const float*)d_in[4];
    const float* Wr  = (const float*)d_in[5];
    const float* br  = (const float*)d_in[6];
    float* out = (float*)d_out;

    const int n = in_sizes[0] / 64;            // 50000
    const int e = in_sizes[1];                 // 800000
    const int nb = (e + TILE - 1) / TILE;      // 196 bucket blocks
    const int nrange = (n + 255) / 256;        // 196 node ranges
    const int m = 2 * 256 * nb;                // 100352 hist entries
    const int nbs = (m + 4095) / 4096;         // 25 scan blocks

    int*   H      = (int*)d_ws;                // m
    int*   Hoff   = H + m;                     // m
    int*   part   = Hoff + m;                  // 256
    int*   packed = part + 256;                // e
    int*   roff   = packed + e;                // n+1
    int*   col    = roff + n + 1;              // e
    float* xs     = (float*)(col + e);         // n*64
    float* agg    = xs + (size_t)n * 64;       // n*64
    unsigned char* ksrc2 = (unsigned char*)(agg + (size_t)n * 64); // e bytes

    bucket_hist_kernel<<<nb, 256, 0, stream>>>(src, dst, H, e, nb);

    partial_kernel<<<nbs, 256, 0, stream>>>(H, part, m);
    scan_final_kernel<<<nbs, 256, 0, stream>>>(H, part, Hoff, m, nbs);

    bucket_scatter_kernel<<<nb, 256, 0, stream>>>(src, dst, Hoff, packed, ksrc2, e, nb);

    csr_outdeg_kernel<<<2 * nrange, 256, 0, stream>>>(
        packed, ksrc2, Hoff, roff, col, (const float4*)x, (float4*)xs, n, e, nb, nrange);

    gather_kernel<<<(n * 64 + 255) / 256, 256, 0, stream>>>(
        (const float4*)xs, col, roff, (float4*)agg, n);

    out_kernel<<<(n + OR - 1) / OR, 256, 0, stream>>>(
        (const float4*)agg, (const float4*)x, W, b, Wr, br, out, n);
}

// Round 13
// 104.638 us; speedup vs baseline: 4.0859x; 1.1259x over previous
//
#include <hip/hip_runtime.h>

// ---------------------------------------------------------------------------
// GraphConv (DGL norm='both') + residual linear:
//   out = (D_dst^-1/2 * A^T * (D_src^-1/2 * x)) @ W + x @ Wr + (b + br)
// Round 13: R12 structure + fp16 xs (halves gather row traffic) and ushort
// col indices (halves index traffic). Zero global atomics, 7 launches.
// ---------------------------------------------------------------------------

#define TILE 4096   // edges per bucket block

typedef __attribute__((ext_vector_type(4))) _Float16 half4;

// Per-block LDS histograms of dst>>8 and src>>8.
// H layout: H[bin*nb + blk] (dst), H[256*nb + bin*nb + blk] (src).
__global__ __launch_bounds__(256) void bucket_hist_kernel(
    const int* __restrict__ src, const int* __restrict__ dst,
    int* __restrict__ H, int e, int nb) {
    __shared__ int hd[256], hs[256];
    int t = threadIdx.x, blk = blockIdx.x;
    hd[t] = 0; hs[t] = 0;
    __syncthreads();
    int base = blk * TILE;
    #pragma unroll
    for (int s = 0; s < 16; ++s) {
        int j = base + s * 256 + t;
        if (j < e) {
            atomicAdd(&hd[dst[j] >> 8], 1);
            atomicAdd(&hs[src[j] >> 8], 1);
        }
    }
    __syncthreads();
    H[t * nb + blk]            = hd[t];
    H[256 * nb + t * nb + blk] = hs[t];
}

// Scan phase A: 4096 elems/block partial sums.
__global__ void partial_kernel(const int* __restrict__ cnt, int* __restrict__ part, int m) {
    __shared__ int sm[256];
    int t = threadIdx.x;
    int base = blockIdx.x * 4096 + t * 16;
    int s = 0;
    if (base + 16 <= m) {
        const int4* p = (const int4*)(cnt + base);
        #pragma unroll
        for (int k = 0; k < 4; ++k) { int4 v = p[k]; s += v.x + v.y + v.z + v.w; }
    } else {
        for (int k = 0; k < 16; ++k) if (base + k < m) s += cnt[base + k];
    }
    sm[t] = s;
    __syncthreads();
    for (int st = 128; st > 0; st >>= 1) {
        if (t < st) sm[t] += sm[t + st];
        __syncthreads();
    }
    if (t == 0) part[blockIdx.x] = sm[0];
}

// Scan phase B+C fused: each block redundantly exclusive-scans the (<=256)
// partials in LDS, then does its local 4096-elem exclusive scan -> Hoff.
__global__ void scan_final_kernel(const int* __restrict__ cnt, const int* __restrict__ part,
                                  int* __restrict__ Hoff, int m, int nbs) {
    __shared__ int sm[256], sp[256];
    int t = threadIdx.x;
    int pv = (t < nbs) ? part[t] : 0;
    sp[t] = pv;
    __syncthreads();
    for (int d = 1; d < 256; d <<= 1) {
        int add = (t >= d) ? sp[t - d] : 0;
        __syncthreads();
        sp[t] += add;
        __syncthreads();
    }
    sp[t] -= pv;   // exclusive
    __syncthreads();
    int blkoff = sp[blockIdx.x];

    int base = blockIdx.x * 4096 + t * 16;
    int v[16];
    #pragma unroll
    for (int k = 0; k < 16; ++k) v[k] = (base + k < m) ? cnt[base + k] : 0;
    int s = 0;
    #pragma unroll
    for (int k = 0; k < 16; ++k) { int x = v[k]; v[k] = s; s += x; }
    sm[t] = s;
    __syncthreads();
    for (int d = 1; d < 256; d <<= 1) {
        int add = (t >= d) ? sm[t - d] : 0;
        __syncthreads();
        sm[t] += add;
        __syncthreads();
    }
    int tb = sm[t] - s + blkoff;
    #pragma unroll
    for (int k = 0; k < 16; ++k)
        if (base + k < m) Hoff[base + k] = v[k] + tb;
}

// Scatter edges into range buckets. packed = (src<<8)|(dst&255) into dst
// buckets; 1-byte (src&255) into src buckets. LDS cursors, cached stores.
__global__ __launch_bounds__(256) void bucket_scatter_kernel(
    const int* __restrict__ src, const int* __restrict__ dst,
    const int* __restrict__ Hoff,
    int* __restrict__ packed, unsigned char* __restrict__ ksrc2,
    int e, int nb) {
    __shared__ int dcur[256], scur[256];
    int t = threadIdx.x, blk = blockIdx.x;
    dcur[t] = Hoff[t * nb + blk];
    scur[t] = Hoff[256 * nb + t * nb + blk] - e;   // src offsets live in [e,2e)
    __syncthreads();
    int base = blk * TILE;
    #pragma unroll
    for (int s2 = 0; s2 < 16; ++s2) {
        int j = base + s2 * 256 + t;
        if (j < e) {
            int d = dst[j], sv = src[j];
            int pd = atomicAdd(&dcur[d >> 8], 1);
            packed[pd] = (sv << 8) | (d & 255);
            int ps = atomicAdd(&scur[sv >> 8], 1);
            ksrc2[ps] = (unsigned char)(sv & 255);
        }
    }
}

// Fused grid: blocks [0,nrange) build CSR (roff + ushort col); blocks
// [nrange,2*nrange) compute out-degree + fp16 prescale of x.
__global__ __launch_bounds__(256) void csr_outdeg_kernel(
    const int* __restrict__ packed, const unsigned char* __restrict__ ksrc2,
    const int* __restrict__ Hoff,
    int* __restrict__ roff, unsigned short* __restrict__ col,
    const float4* __restrict__ x4, half4* __restrict__ xsh,
    int n, int e, int nb, int nrange) {
    __shared__ int lh[256], sm[256];
    int t = threadIdx.x;
    int r = blockIdx.x;
    if (r < nrange) {
        // ---- CSR build for dst range r ----
        int beg = Hoff[r * nb];
        int end = (r + 1 < nrange) ? Hoff[(r + 1) * nb] : e;
        lh[t] = 0;
        __syncthreads();
        for (int j = beg + t; j < end; j += 256)
            atomicAdd(&lh[packed[j] & 255], 1);
        __syncthreads();
        int v0 = lh[t];
        sm[t] = v0;
        __syncthreads();
        for (int d = 1; d < 256; d <<= 1) {
            int add = (t >= d) ? sm[t - d] : 0;
            __syncthreads();
            sm[t] += add;
            __syncthreads();
        }
        int excl = sm[t] - v0;
        int v = r * 256 + t;
        if (v < n) roff[v] = beg + excl;
        __syncthreads();          // all v0 reads done before lh reuse
        lh[t] = excl;             // lh becomes the local cursor array
        __syncthreads();
        for (int j = beg + t; j < end; j += 256) {
            int p = packed[j];
            int pos = beg + atomicAdd(&lh[p & 255], 1);
            col[pos] = (unsigned short)(p >> 8);
        }
        if (r == 0 && t == 0) roff[n] = e;
    } else {
        // ---- out-degree + fp16 prescale for src range r-nrange ----
        r -= nrange;
        lh[t] = 0;
        __syncthreads();
        int beg = Hoff[256 * nb + r * nb] - e;
        int end = (r + 1 < nrange) ? (Hoff[256 * nb + (r + 1) * nb] - e) : e;
        for (int j = beg + t; j < end; j += 256)
            atomicAdd(&lh[ksrc2[j]], 1);
        __syncthreads();
        int base = r * 256;
        for (int i = t; i < 256 * 16; i += 256) {
            int row = i >> 4, g = base + row;
            if (g < n) {
                float s = rsqrtf((float)max(lh[row], 1));
                float4 v = x4[(long)g * 16 + (i & 15)];
                half4 h;
                h.x = (_Float16)(v.x * s);
                h.y = (_Float16)(v.y * s);
                h.z = (_Float16)(v.z * s);
                h.w = (_Float16)(v.w * s);
                xsh[(long)g * 16 + (i & 15)] = h;
            }
        }
    }
}

// One wave per node. Lane = (edge-slot g = lane>>4) x (feature-quad q = lane&15).
// agg[node] = rsqrt(max(in_deg,1)) * sum_{s in N(node)} xs[s]  (xs is fp16).
__global__ __launch_bounds__(256) void gather_kernel(
    const half4* __restrict__ xsh, const unsigned short* __restrict__ col,
    const int* __restrict__ roff,
    float4* __restrict__ agg4, int n) {
    int lane = threadIdx.x & 63;
    int node = (blockIdx.x * 256 + threadIdx.x) >> 6;
    if (node >= n) return;
    node = __builtin_amdgcn_readfirstlane(node);   // wave-uniform -> scalar loads

    int beg = roff[node];
    int end = roff[node + 1];
    int g = lane >> 4;   // edge sub-slot 0..3
    int q = lane & 15;   // feature quad 0..15

    float4 acc = make_float4(0.f, 0.f, 0.f, 0.f);
    int j = beg;
    for (; j + 16 <= end; j += 16) {        // 16 edges: 4 x 8B loads in flight
        int s0 = col[j + g];
        int s1 = col[j + 4 + g];
        int s2 = col[j + 8 + g];
        int s3 = col[j + 12 + g];
        half4 v0 = xsh[(long)s0 * 16 + q];
        half4 v1 = xsh[(long)s1 * 16 + q];
        half4 v2 = xsh[(long)s2 * 16 + q];
        half4 v3 = xsh[(long)s3 * 16 + q];
        acc.x += ((float)v0.x + (float)v1.x) + ((float)v2.x + (float)v3.x);
        acc.y += ((float)v0.y + (float)v1.y) + ((float)v2.y + (float)v3.y);
        acc.z += ((float)v0.z + (float)v1.z) + ((float)v2.z + (float)v3.z);
        acc.w += ((float)v0.w + (float)v1.w) + ((float)v2.w + (float)v3.w);
    }
    for (; j + 8 <= end; j += 8) {
        int s0 = col[j + g];
        int s1 = col[j + 4 + g];
        half4 v0 = xsh[(long)s0 * 16 + q];
        half4 v1 = xsh[(long)s1 * 16 + q];
        acc.x += (float)v0.x + (float)v1.x;
        acc.y += (float)v0.y + (float)v1.y;
        acc.z += (float)v0.z + (float)v1.z;
        acc.w += (float)v0.w + (float)v1.w;
    }
    for (; j < end; j += 4) {               // predicated 4-edge tail
        int jj = j + g;
        int s   = (jj < end) ? (int)col[jj] : node;   // safe dummy index
        float m = (jj < end) ? 1.f : 0.f;
        half4 v = xsh[(long)s * 16 + q];
        acc.x += (float)v.x * m;
        acc.y += (float)v.y * m;
        acc.z += (float)v.z * m;
        acc.w += (float)v.w * m;
    }

    acc.x += __shfl_down(acc.x, 32);
    acc.y += __shfl_down(acc.y, 32);
    acc.z += __shfl_down(acc.z, 32);
    acc.w += __shfl_down(acc.w, 32);
    acc.x += __shfl_down(acc.x, 16);
    acc.y += __shfl_down(acc.y, 16);
    acc.z += __shfl_down(acc.z, 16);
    acc.w += __shfl_down(acc.w, 16);

    float nd = rsqrtf((float)max(end - beg, 1));
    if (lane < 16) {
        acc.x *= nd; acc.y *= nd; acc.z *= nd; acc.w *= nd;
        agg4[(long)node * 16 + q] = acc;
    }
}

// out[r][c] = agg[r][:]@W[:,c] + x[r][:]@Wr[:,c] + (b+br)[c]
// Lane c holds W[:,c], Wr[:,c] in VGPRs (static unroll); rows staged in LDS.
#define OR 32
__global__ __launch_bounds__(256) void out_kernel(
    const float4* __restrict__ agg4, const float4* __restrict__ x4,
    const float* __restrict__ W, const float* __restrict__ b,
    const float* __restrict__ Wr, const float* __restrict__ br,
    float* __restrict__ out, int n) {
    __shared__ float4 sA[OR * 16];
    __shared__ float4 sX[OR * 16];
    int t = threadIdx.x;
    int c = t & 63;
    int base = blockIdx.x * OR;

    float4 wA[16], wR[16];
    #pragma unroll
    for (int q = 0; q < 16; ++q) {
        wA[q].x = W[(4 * q + 0) * 64 + c];
        wA[q].y = W[(4 * q + 1) * 64 + c];
        wA[q].z = W[(4 * q + 2) * 64 + c];
        wA[q].w = W[(4 * q + 3) * 64 + c];
        wR[q].x = Wr[(4 * q + 0) * 64 + c];
        wR[q].y = Wr[(4 * q + 1) * 64 + c];
        wR[q].z = Wr[(4 * q + 2) * 64 + c];
        wR[q].w = Wr[(4 * q + 3) * 64 + c];
    }

    #pragma unroll
    for (int i = 0; i < 2; ++i) {          // stage 32 rows of A and X
        int qi = t + 256 * i;              // 0..511
        int row = base + (qi >> 4);
        float4 z = make_float4(0.f, 0.f, 0.f, 0.f);
        sA[qi] = (row < n) ? agg4[(long)row * 16 + (qi & 15)] : z;
        sX[qi] = (row < n) ? x4[(long)row * 16 + (qi & 15)] : z;
    }
    __syncthreads();

    int w = t >> 6;
    float bias = b[c] + br[c];
    for (int r = w * 8; r < w * 8 + 8; ++r) {
        float a0 = 0.f, a1 = 0.f, r0 = 0.f, r1 = 0.f;
        #pragma unroll
        for (int q = 0; q < 16; q += 2) {
            float4 av0 = sA[r * 16 + q];
            float4 av1 = sA[r * 16 + q + 1];
            float4 xv0 = sX[r * 16 + q];
            float4 xv1 = sX[r * 16 + q + 1];
            a0 += av0.x * wA[q].x + av0.y * wA[q].y + av0.z * wA[q].z + av0.w * wA[q].w;
            a1 += av1.x * wA[q + 1].x + av1.y * wA[q + 1].y + av1.z * wA[q + 1].z + av1.w * wA[q + 1].w;
            r0 += xv0.x * wR[q].x + xv0.y * wR[q].y + xv0.z * wR[q].z + xv0.w * wR[q].w;
            r1 += xv1.x * wR[q + 1].x + xv1.y * wR[q + 1].y + xv1.z * wR[q + 1].z + xv1.w * wR[q + 1].w;
        }
        int grow = base + r;
        if (grow < n) out[(long)grow * 64 + c] = (a0 + a1) + (r0 + r1) + bias;
    }
}

extern "C" void kernel_launch(void* const* d_in, const int* in_sizes, int n_in,
                              void* d_out, int out_size, void* d_ws, size_t ws_size,
                              hipStream_t stream) {
    const float* x   = (const float*)d_in[0];
    const int*   src = (const int*)d_in[1];
    const int*   dst = (const int*)d_in[2];
    const float* W   = (const float*)d_in[3];
    const float* b   = (const float*)d_in[4];
    const float* Wr  = (const float*)d_in[5];
    const float* br  = (const float*)d_in[6];
    float* out = (float*)d_out;

    const int n = in_sizes[0] / 64;            // 50000
    const int e = in_sizes[1];                 // 800000
    const int nb = (e + TILE - 1) / TILE;      // 196 bucket blocks
    const int nrange = (n + 255) / 256;        // 196 node ranges
    const int m = 2 * 256 * nb;                // 100352 hist entries
    const int nbs = (m + 4095) / 4096;         // 25 scan blocks

    char* p = (char*)d_ws;
    int* H      = (int*)p;  p += (size_t)m * 4;
    int* Hoff   = (int*)p;  p += (size_t)m * 4;
    int* part   = (int*)p;  p += 1024;
    int* packed = (int*)p;  p += (size_t)e * 4;
    int* roff   = (int*)p;  p += (size_t)(n + 1) * 4;
    p = (char*)(((uintptr_t)p + 15) & ~(uintptr_t)15);
    unsigned short* col = (unsigned short*)p;  p += (size_t)e * 2;
    p = (char*)(((uintptr_t)p + 15) & ~(uintptr_t)15);
    half4* xsh  = (half4*)p;  p += (size_t)n * 64 * 2;
    p = (char*)(((uintptr_t)p + 15) & ~(uintptr_t)15);
    float* agg  = (float*)p;  p += (size_t)n * 64 * 4;
    unsigned char* ksrc2 = (unsigned char*)p;   // e bytes

    bucket_hist_kernel<<<nb, 256, 0, stream>>>(src, dst, H, e, nb);

    partial_kernel<<<nbs, 256, 0, stream>>>(H, part, m);
    scan_final_kernel<<<nbs, 256, 0, stream>>>(H, part, Hoff, m, nbs);

    bucket_scatter_kernel<<<nb, 256, 0, stream>>>(src, dst, Hoff, packed, ksrc2, e, nb);

    csr_outdeg_kernel<<<2 * nrange, 256, 0, stream>>>(
        packed, ksrc2, Hoff, roff, col, (const float4*)x, xsh, n, e, nb, nrange);

    gather_kernel<<<(n * 64 + 255) / 256, 256, 0, stream>>>(
        xsh, col, roff, (float4*)agg, n);

    out_kernel<<<(n + OR - 1) / OR, 256, 0, stream>>>(
        (const float4*)agg, (const float4*)x, W, b, Wr, br, out, n);
}